// Round 2
// baseline (335.067 us; speedup 1.0000x reference)
//
#include <hip/hip_runtime.h>

// Fused: bicubic 2x upsample -> leaky_relu(0.01) -> antialiased bicubic 2x down.
// NHWC f32, B=16, H=W=128, C=128.
// Block: (batch, 16-row output strip, 16-channel chunk, all 128 cols).
// 256 threads = 16 channels x 16 col-groups (8 output cols each).
// Streaming over coarse rows; register rings rotated by macro renaming
// (no movs); one barrier per coarse step (4 LDS slots); b128 LDS halo
// exchange; branch-free interior horizontal pipeline + static edge fixups.

#define HH 128
#define WW 128
#define CC 128
#define RS 16       // output rows per strip
#define CH 16       // channels per block
#define PAD 132     // LDS row stride in words (16B-aligned cols, even banks)
#define NSTEP (RS + 4)

__device__ __forceinline__ double keys_cubic(double x) {
  // JAX _fill_keys_cubic_kernel (a = -0.5)
  if (x >= 2.0) return 0.0;
  if (x >= 1.0) return ((-0.5 * x + 2.5) * x - 4.0) * x + 2.0;
  return (1.5 * x - 2.5) * x * x + 1.0;
}

__global__ __launch_bounds__(256, 3) void fused_updown_kernel(
    const float* __restrict__ x, float* __restrict__ out) {
  __shared__ __align__(16) float wUpV[256][4];     // fine row/col -> 4 taps
  __shared__ __align__(16) float wDnE[4][8];       // out col 0,1,126,127 -> 8 taps
  __shared__ __align__(16) float rowv[4][CH][PAD]; // 4-slot vert-upsampled rows

  const int tid = threadIdx.x;

  // ---- weight tables (renormalized truncation, matches jax.image.resize) ----
  {
    const int k = tid;
    const double q = 0.5 * k - 0.25;          // sample_f = (k+0.5)/2 - 0.5
    const int st = ((k + 1) >> 1) - 2;
    double wr[4], s = 0.0;
#pragma unroll
    for (int i = 0; i < 4; ++i) {
      const int col = st + i;
      double w = (col >= 0 && col <= 127) ? keys_cubic(fabs((double)col - q)) : 0.0;
      wr[i] = w; s += w;
    }
    const double inv = 1.0 / s;
#pragma unroll
    for (int i = 0; i < 4; ++i) wUpV[k][i] = (float)(wr[i] * inv);
  }
  if (tid < 4) {
    const int e = tid;
    const int j = (e < 2) ? e : 124 + e;      // 0,1,126,127
    const double p = 2.0 * j + 0.5;           // sample_f = (j+0.5)*2 - 0.5
    const int st = 2 * j - 3;
    double wr[8], s = 0.0;
#pragma unroll
    for (int i = 0; i < 8; ++i) {
      const int col = st + i;
      double w = (col >= 0 && col <= 255) ? keys_cubic(0.5 * fabs((double)col - p)) : 0.0;
      wr[i] = w; s += w;
    }
    const double inv = 1.0 / s;
#pragma unroll
    for (int i = 0; i < 8; ++i) wDnE[e][i] = (float)(wr[i] * inv);
  }
  __syncthreads();

  const int bid = blockIdx.x;
  const int b = bid & 15;
  const int strip = (bid >> 4) & 7;
  const int chunk = bid >> 7;
  const int oy0 = strip * RS;
  const int c0 = chunk * CH;
  const int c = tid & 15;                      // channel (lane-contiguous)
  const int g = tid >> 4;                      // col group 0..15
  const int col0 = g * 8;
  const bool gL = (g == 0), gR = (g == 15);

  const float* xbase = x + (size_t)b * (HH * WW * CC) + (size_t)col0 * CC + (c0 + c);
  float* obase = out + (size_t)b * (HH * WW * CC) + (size_t)col0 * CC + (c0 + c);
  const int m0 = oy0 - 2;

  auto load_row = [&](float (&d)[8], int row) {
    row = row < 0 ? 0 : (row > 127 ? 127 : row);
    const float* p = xbase + (size_t)row * (WW * CC);
#pragma unroll
    for (int j = 0; j < 8; ++j) d[j] = p[j * CC];
  };

  // vertical-downsample weight for output row oy at tap (interior const cst)
  auto wdGet = [&](int oy, float cst, int tap) -> float {
    if (oy < 0 || oy > 127) return 0.f;
    if (oy < 2) return wDnE[oy][tap];
    if (oy > 125) return wDnE[oy - 124][tap];
    return cst;
  };

  // horizontal pipeline for one fine row already staged in LDS slot sl
  auto proc = [&](int sl, const float (&vm)[8], float w0, float w1, float w2, float w3,
                  float (&B0)[8], float (&B1)[8], float (&B2)[8], float (&B3)[8]) {
    float v[16];
    if (!gL) {
      const float4 h = *(const float4*)&rowv[sl][c][col0 - 4];
      v[0] = h.x; v[1] = h.y; v[2] = h.z; v[3] = h.w;
    } else { v[0] = v[1] = v[2] = v[3] = 0.f; }
#pragma unroll
    for (int j = 0; j < 8; ++j) v[4 + j] = vm[j];
    if (!gR) {
      const float4 h = *(const float4*)&rowv[sl][c][col0 + 8];
      v[12] = h.x; v[13] = h.y; v[14] = h.z; v[15] = h.w;
    } else { v[12] = v[13] = v[14] = v[15] = 0.f; }

    // fine cols k0..k0+21, interior constants for everyone
    float f[22];
#pragma unroll
    for (int u = 0; u < 22; ++u) {
      const int s = (u >> 1) + 1;
      float t;
      if (u & 1)
        t = fmaf(-0.0234375f, v[s], fmaf(0.2265625f, v[s + 1],
            fmaf(0.8671875f, v[s + 2], -0.0703125f * v[s + 3])));
      else
        t = fmaf(-0.0703125f, v[s], fmaf(0.8671875f, v[s + 1],
            fmaf(0.2265625f, v[s + 2], -0.0234375f * v[s + 3])));
      f[u] = fmaxf(t, 0.01f * t);
    }
    if (gL) {              // fine cols 0,1,2 need boundary weights (k0 = -3)
#pragma unroll
      for (int u = 3; u <= 5; ++u) {
        const int s = (u >> 1) + 1;
        const float4 w = *(const float4*)wUpV[u - 3];
        const float t = fmaf(w.x, v[s], fmaf(w.y, v[s + 1],
                        fmaf(w.z, v[s + 2], w.w * v[s + 3])));
        f[u] = fmaxf(t, 0.01f * t);
      }
    }
    if (gR) {              // fine cols 253,254,255 (k0 = 237)
#pragma unroll
      for (int u = 16; u <= 18; ++u) {
        const int s = (u >> 1) + 1;
        const float4 w = *(const float4*)wUpV[237 + u];
        const float t = fmaf(w.x, v[s], fmaf(w.y, v[s + 1],
                        fmaf(w.z, v[s + 2], w.w * v[s + 3])));
        f[u] = fmaxf(t, 0.01f * t);
      }
    }
    // horizontal downsample (interior symmetric 8-tap)
    float tt[8];
#pragma unroll
    for (int jj = 0; jj < 8; ++jj) {
      tt[jj] = fmaf(-0.01171875f, f[2 * jj] + f[2 * jj + 7],
               fmaf(-0.03515625f, f[2 * jj + 1] + f[2 * jj + 6],
               fmaf(0.11328125f, f[2 * jj + 2] + f[2 * jj + 5],
                    0.43359375f * (f[2 * jj + 3] + f[2 * jj + 4]))));
    }
    if (gL) {              // out cols 0,1 via table
#pragma unroll
      for (int jj = 0; jj < 2; ++jj) {
        float s2 = 0.f;
#pragma unroll
        for (int i = 0; i < 8; ++i) s2 = fmaf(wDnE[jj][i], f[2 * jj + i], s2);
        tt[jj] = s2;
      }
    }
    if (gR) {              // out cols 126,127 via table
#pragma unroll
      for (int jj = 6; jj < 8; ++jj) {
        float s2 = 0.f;
#pragma unroll
        for (int i = 0; i < 8; ++i) s2 = fmaf(wDnE[jj - 4][i], f[2 * jj + i], s2);
        tt[jj] = s2;
      }
    }
    // vertical-downsample scatter into 4 rotating accumulators
#pragma unroll
    for (int jj = 0; jj < 8; ++jj) {
      B0[jj] = fmaf(w0, tt[jj], B0[jj]);
      B1[jj] = fmaf(w1, tt[jj], B1[jj]);
      B2[jj] = fmaf(w2, tt[jj], B2[jj]);
      B3[jj] = fmaf(w3, tt[jj], B3[jj]);
    }
  };

  float R0[8], R1[8], R2[8], R3[8], R4[8];
  float A0[8], A1[8], A2[8], A3[8], A4[8];
#pragma unroll
  for (int i = 0; i < 8; ++i) {
    R0[i] = 0.f; A0[i] = 0.f; A1[i] = 0.f; A2[i] = 0.f; A3[i] = 0.f; A4[i] = 0.f;
  }
  load_row(R1, m0 - 1);
  load_row(R2, m0);
  load_row(R3, m0 + 1);

// One coarse step: rows Ra..Rd = m-2..m+1 at entry; loads Re = m+2;
// processes fine rows 2m (even) and 2m+1 (odd); stores+zeros Pa (oy = m-2).
#define STEP(Ra, Rb, Rc, Rd, Re, Pa, Pb, Pc, Pd, Pe, T)                          \
  do {                                                                           \
    const int m = m0 + (T);                                                      \
    if ((T) <= RS + 2) load_row(Re, m + 2);                                      \
    const bool mOK = (m >= 0) && (m <= 127);                                     \
    const bool evOK = mOK && ((T) >= 1);                                         \
    const bool odOK = mOK && ((T) <= RS + 2);                                    \
    const int sp = ((T) & 1) * 2;                                                \
    float vE[8], vO[8];                                                          \
    if (evOK) {                                                                  \
      const float4 wv = *(const float4*)wUpV[2 * m];                             \
      _Pragma("unroll") for (int j = 0; j < 8; ++j)                              \
          vE[j] = fmaf(wv.x, Ra[j], fmaf(wv.y, Rb[j],                            \
                  fmaf(wv.z, Rc[j], wv.w * Rd[j])));                             \
      *(float4*)&rowv[sp][c][col0] = make_float4(vE[0], vE[1], vE[2], vE[3]);    \
      *(float4*)&rowv[sp][c][col0 + 4] = make_float4(vE[4], vE[5], vE[6], vE[7]);\
    }                                                                            \
    if (odOK) {                                                                  \
      const float4 wv = *(const float4*)wUpV[2 * m + 1];                         \
      _Pragma("unroll") for (int j = 0; j < 8; ++j)                              \
          vO[j] = fmaf(wv.x, Rb[j], fmaf(wv.y, Rc[j],                            \
                  fmaf(wv.z, Rd[j], wv.w * Re[j])));                             \
      *(float4*)&rowv[sp + 1][c][col0] = make_float4(vO[0], vO[1], vO[2], vO[3]);\
      *(float4*)&rowv[sp + 1][c][col0 + 4] =                                     \
          make_float4(vO[4], vO[5], vO[6], vO[7]);                               \
    }                                                                            \
    __syncthreads();                                                             \
    if (evOK)                                                                    \
      proc(sp, vE, wdGet(m - 2, -0.01171875f, 7), wdGet(m - 1, 0.11328125f, 5),  \
           wdGet(m, 0.43359375f, 3), wdGet(m + 1, -0.03515625f, 1),              \
           Pa, Pb, Pc, Pd);                                                      \
    if (odOK)                                                                    \
      proc(sp + 1, vO, wdGet(m - 1, -0.03515625f, 6), wdGet(m, 0.43359375f, 4),  \
           wdGet(m + 1, 0.11328125f, 2), wdGet(m + 2, -0.01171875f, 0),          \
           Pb, Pc, Pd, Pe);                                                      \
    if (m - 2 >= oy0) {                                                          \
      float* op = obase + (size_t)(m - 2) * (WW * CC);                           \
      _Pragma("unroll") for (int jj = 0; jj < 8; ++jj) op[jj * CC] = Pa[jj];     \
    }                                                                            \
    _Pragma("unroll") for (int jj = 0; jj < 8; ++jj) Pa[jj] = 0.f;               \
  } while (0)

  for (int tb = 0; tb < NSTEP; tb += 5) {
    STEP(R0, R1, R2, R3, R4, A0, A1, A2, A3, A4, tb + 0);
    STEP(R1, R2, R3, R4, R0, A1, A2, A3, A4, A0, tb + 1);
    STEP(R2, R3, R4, R0, R1, A2, A3, A4, A0, A1, tb + 2);
    STEP(R3, R4, R0, R1, R2, A3, A4, A0, A1, A2, tb + 3);
    STEP(R4, R0, R1, R2, R3, A4, A0, A1, A2, A3, tb + 4);
  }
#undef STEP
}

extern "C" void kernel_launch(void* const* d_in, const int* in_sizes, int n_in,
                              void* d_out, int out_size, void* d_ws, size_t ws_size,
                              hipStream_t stream) {
  const float* x = (const float*)d_in[0];
  float* o = (float*)d_out;
  dim3 grid(16 * 8 * 8);   // batch(16) x strips(8) x channel-chunks(8)
  dim3 block(256);
  hipLaunchKernelGGL(fused_updown_kernel, grid, block, 0, stream, x, o);
}

// Round 3
// 105.094 us; speedup vs baseline: 3.1883x; 3.1883x over previous
//
#include <hip/hip_runtime.h>

// Fused: bicubic 2x upsample -> leaky_relu(0.01) -> antialiased bicubic 2x down.
// NHWC f32, B=16, H=W=128, C=128.
// Round 3 = round-1 scheduling structure (rolled loop, mov rotation, inlined
// lambdas at 2 call sites) + RS=16 + single barrier/step + b128 LDS exchange
// + branch-free interior horizontal pipeline with static edge fixups.

#define HH 128
#define WW 128
#define CC 128
#define RS 16       // output rows per strip
#define CH 16       // channels per block
#define PAD 132     // LDS row stride in words (16B-aligned, balanced banks)
#define NSTEP (RS + 4)

__device__ __forceinline__ double keys_cubic(double x) {
  // JAX _fill_keys_cubic_kernel (a = -0.5)
  if (x >= 2.0) return 0.0;
  if (x >= 1.0) return ((-0.5 * x + 2.5) * x - 4.0) * x + 2.0;
  return (1.5 * x - 2.5) * x * x + 1.0;
}

__global__ __launch_bounds__(256) void fused_updown_kernel(
    const float* __restrict__ x, float* __restrict__ out) {
  __shared__ __align__(16) float wUpV[256][4];     // fine row/col -> 4 taps
  __shared__ __align__(16) float wDnE[4][8];       // out col 0,1,126,127 -> 8 taps
  __shared__ __align__(16) float rowv[4][CH][PAD]; // 4-slot vert-upsampled rows

  const int tid = threadIdx.x;

  // ---- weight tables (renormalized truncation, matches jax.image.resize) ----
  {
    const int k = tid;
    const double q = 0.5 * k - 0.25;          // sample_f = (k+0.5)/2 - 0.5
    const int st = ((k + 1) >> 1) - 2;
    double wr[4], s = 0.0;
#pragma unroll
    for (int i = 0; i < 4; ++i) {
      const int col = st + i;
      double w = (col >= 0 && col <= 127) ? keys_cubic(fabs((double)col - q)) : 0.0;
      wr[i] = w; s += w;
    }
    const double inv = 1.0 / s;
#pragma unroll
    for (int i = 0; i < 4; ++i) wUpV[k][i] = (float)(wr[i] * inv);
  }
  if (tid < 4) {
    const int e = tid;
    const int j = (e < 2) ? e : 124 + e;      // 0,1,126,127
    const double p = 2.0 * j + 0.5;           // sample_f = (j+0.5)*2 - 0.5
    const int st = 2 * j - 3;
    double wr[8], s = 0.0;
#pragma unroll
    for (int i = 0; i < 8; ++i) {
      const int col = st + i;
      double w = (col >= 0 && col <= 255) ? keys_cubic(0.5 * fabs((double)col - p)) : 0.0;
      wr[i] = w; s += w;
    }
    const double inv = 1.0 / s;
#pragma unroll
    for (int i = 0; i < 8; ++i) wDnE[e][i] = (float)(wr[i] * inv);
  }
  __syncthreads();

  const int bid = blockIdx.x;
  const int b = bid & 15;
  const int strip = (bid >> 4) & 7;
  const int chunk = bid >> 7;
  const int oy0 = strip * RS;
  const int c0 = chunk * CH;
  const int c = tid & 15;                      // channel (lane-contiguous)
  const int g = tid >> 4;                      // col group 0..15
  const int col0 = g * 8;
  const bool gL = (g == 0), gR = (g == 15);

  const float* xbase = x + (size_t)b * (HH * WW * CC) + (size_t)col0 * CC + (c0 + c);
  float* obase = out + (size_t)b * (HH * WW * CC) + (size_t)col0 * CC + (c0 + c);
  const int m0 = oy0 - 2;

  auto load_row = [&](float (&d)[8], int row) {
    row = row < 0 ? 0 : (row > 127 ? 127 : row);
    const float* p = xbase + (size_t)row * (WW * CC);
#pragma unroll
    for (int j = 0; j < 8; ++j) d[j] = p[j * CC];
  };

  // vertical-downsample weight for output row oy at tap (interior const cst)
  auto wdGet = [&](int oy, float cst, int tap) -> float {
    if (oy < 0 || oy > 127) return 0.f;
    if (oy < 2) return wDnE[oy][tap];
    if (oy > 125) return wDnE[oy - 124][tap];
    return cst;
  };

  // horizontal pipeline for one fine row; own 8 vals in vm, halos in LDS slot sl
  auto proc = [&](int sl, const float (&vm)[8], float w0, float w1, float w2, float w3,
                  float (&B0)[8], float (&B1)[8], float (&B2)[8], float (&B3)[8]) {
    float v[16];
    if (!gL) {
      const float4 h = *(const float4*)&rowv[sl][c][col0 - 4];
      v[0] = h.x; v[1] = h.y; v[2] = h.z; v[3] = h.w;
    } else { v[0] = v[1] = v[2] = v[3] = 0.f; }
#pragma unroll
    for (int j = 0; j < 8; ++j) v[4 + j] = vm[j];
    if (!gR) {
      const float4 h = *(const float4*)&rowv[sl][c][col0 + 8];
      v[12] = h.x; v[13] = h.y; v[14] = h.z; v[15] = h.w;
    } else { v[12] = v[13] = v[14] = v[15] = 0.f; }

    // horizontal upsample + leaky, fine cols k0..k0+21 (interior constants)
    float f[22];
#pragma unroll
    for (int u = 0; u < 22; ++u) {
      const int s = (u >> 1) + 1;
      float t;
      if (u & 1)
        t = fmaf(-0.0234375f, v[s], fmaf(0.2265625f, v[s + 1],
            fmaf(0.8671875f, v[s + 2], -0.0703125f * v[s + 3])));
      else
        t = fmaf(-0.0703125f, v[s], fmaf(0.8671875f, v[s + 1],
            fmaf(0.2265625f, v[s + 2], -0.0234375f * v[s + 3])));
      f[u] = fmaxf(t, 0.01f * t);
    }
    if (gL) {              // fine cols 0,1,2 boundary weights (k0 = -3)
#pragma unroll
      for (int u = 3; u <= 5; ++u) {
        const int s = (u >> 1) + 1;
        const float4 w = *(const float4*)wUpV[u - 3];
        const float t = fmaf(w.x, v[s], fmaf(w.y, v[s + 1],
                        fmaf(w.z, v[s + 2], w.w * v[s + 3])));
        f[u] = fmaxf(t, 0.01f * t);
      }
    }
    if (gR) {              // fine cols 253,254,255 (k0 = 237)
#pragma unroll
      for (int u = 16; u <= 18; ++u) {
        const int s = (u >> 1) + 1;
        const float4 w = *(const float4*)wUpV[237 + u];
        const float t = fmaf(w.x, v[s], fmaf(w.y, v[s + 1],
                        fmaf(w.z, v[s + 2], w.w * v[s + 3])));
        f[u] = fmaxf(t, 0.01f * t);
      }
    }
    // horizontal downsample (interior symmetric 8-tap)
    float tt[8];
#pragma unroll
    for (int jj = 0; jj < 8; ++jj) {
      tt[jj] = fmaf(-0.01171875f, f[2 * jj] + f[2 * jj + 7],
               fmaf(-0.03515625f, f[2 * jj + 1] + f[2 * jj + 6],
               fmaf(0.11328125f, f[2 * jj + 2] + f[2 * jj + 5],
                    0.43359375f * (f[2 * jj + 3] + f[2 * jj + 4]))));
    }
    if (gL) {
#pragma unroll
      for (int jj = 0; jj < 2; ++jj) {
        float s2 = 0.f;
#pragma unroll
        for (int i = 0; i < 8; ++i) s2 = fmaf(wDnE[jj][i], f[2 * jj + i], s2);
        tt[jj] = s2;
      }
    }
    if (gR) {
#pragma unroll
      for (int jj = 6; jj < 8; ++jj) {
        float s2 = 0.f;
#pragma unroll
        for (int i = 0; i < 8; ++i) s2 = fmaf(wDnE[jj - 4][i], f[2 * jj + i], s2);
        tt[jj] = s2;
      }
    }
    // vertical-downsample scatter into 4 rotating accumulators
#pragma unroll
    for (int jj = 0; jj < 8; ++jj) {
      B0[jj] = fmaf(w0, tt[jj], B0[jj]);
      B1[jj] = fmaf(w1, tt[jj], B1[jj]);
      B2[jj] = fmaf(w2, tt[jj], B2[jj]);
      B3[jj] = fmaf(w3, tt[jj], B3[jj]);
    }
  };

  float r0[8], r1[8], r2[8], r3[8], r4[8];
  float A0[8], A1[8], A2[8], A3[8], A4[8];
#pragma unroll
  for (int i = 0; i < 8; ++i) { A0[i]=0.f; A1[i]=0.f; A2[i]=0.f; A3[i]=0.f; A4[i]=0.f; }

  load_row(r0, m0 - 2);
  load_row(r1, m0 - 1);
  load_row(r2, m0);
  load_row(r3, m0 + 1);
  load_row(r4, m0 + 2);

  for (int t = 0; t < NSTEP; ++t) {
    const int m = m0 + t;
    if (t > 0) {
#pragma unroll
      for (int i = 0; i < 8; ++i) { r0[i]=r1[i]; r1[i]=r2[i]; r2[i]=r3[i]; r3[i]=r4[i]; }
      load_row(r4, m + 2);
    }
    const bool mOK = (m >= 0) && (m <= 127);
    const bool evOK = mOK && (t >= 1);
    const bool odOK = mOK && (t <= RS + 2);
    const int sp = (t & 1) * 2;
    float vE[8], vO[8];
    if (evOK) {                                // fine row 2m from rows m-2..m+1
      const float4 wv = *(const float4*)wUpV[2 * m];
#pragma unroll
      for (int j = 0; j < 8; ++j)
        vE[j] = fmaf(wv.x, r0[j], fmaf(wv.y, r1[j], fmaf(wv.z, r2[j], wv.w * r3[j])));
      *(float4*)&rowv[sp][c][col0]     = make_float4(vE[0], vE[1], vE[2], vE[3]);
      *(float4*)&rowv[sp][c][col0 + 4] = make_float4(vE[4], vE[5], vE[6], vE[7]);
    }
    if (odOK) {                                // fine row 2m+1 from rows m-1..m+2
      const float4 wv = *(const float4*)wUpV[2 * m + 1];
#pragma unroll
      for (int j = 0; j < 8; ++j)
        vO[j] = fmaf(wv.x, r1[j], fmaf(wv.y, r2[j], fmaf(wv.z, r3[j], wv.w * r4[j])));
      *(float4*)&rowv[sp + 1][c][col0]     = make_float4(vO[0], vO[1], vO[2], vO[3]);
      *(float4*)&rowv[sp + 1][c][col0 + 4] = make_float4(vO[4], vO[5], vO[6], vO[7]);
    }
    __syncthreads();
    if (evOK)
      proc(sp, vE, wdGet(m - 2, -0.01171875f, 7), wdGet(m - 1, 0.11328125f, 5),
           wdGet(m, 0.43359375f, 3), wdGet(m + 1, -0.03515625f, 1),
           A0, A1, A2, A3);
    if (odOK)
      proc(sp + 1, vO, wdGet(m - 1, -0.03515625f, 6), wdGet(m, 0.43359375f, 4),
           wdGet(m + 1, 0.11328125f, 2), wdGet(m + 2, -0.01171875f, 0),
           A1, A2, A3, A4);
    if (m - 2 >= oy0) {
      float* op = obase + (size_t)(m - 2) * (WW * CC);
#pragma unroll
      for (int jj = 0; jj < 8; ++jj) op[jj * CC] = A0[jj];
    }
#pragma unroll
    for (int jj = 0; jj < 8; ++jj) { A0[jj]=A1[jj]; A1[jj]=A2[jj]; A2[jj]=A3[jj]; A3[jj]=A4[jj]; A4[jj]=0.f; }
  }
}

extern "C" void kernel_launch(void* const* d_in, const int* in_sizes, int n_in,
                              void* d_out, int out_size, void* d_ws, size_t ws_size,
                              hipStream_t stream) {
  const float* x = (const float*)d_in[0];
  float* o = (float*)d_out;
  dim3 grid(16 * 8 * 8);   // batch(16) x strips(8) x channel-chunks(8)
  dim3 block(256);
  hipLaunchKernelGGL(fused_updown_kernel, grid, block, 0, stream, x, o);
}